// Round 4
// baseline (251.109 us; speedup 1.0000x reference)
//
#include <hip/hip_runtime.h>

#define AS1 __attribute__((address_space(1)))
#define AS3 __attribute__((address_space(3)))

typedef __bf16 bf16x8 __attribute__((ext_vector_type(8)));
typedef float f32x4 __attribute__((ext_vector_type(4)));

static constexpr int C = 768;
static constexpr int NB = 128;    // N1 == N2
static constexpr int S  = 256;    // W*H
static constexpr int XY_ELEMS  = NB * NB * S;  // 4194304
static constexpr int XSQ_ELEMS = NB * S;       // 32768
static constexpr size_t WS_TENSOR = (size_t)S * NB * C;  // shorts per tensor

// ---------------------------------------------------------------------------
// Fused producer-consumer kernel.
//  blocks [0,2048):   pass1 role — transpose [n][c][s] fp32 -> [s][n][c] bf16
//                     + fused square-mean. st-slice = blockIdx>>9 so slices
//                     complete in ascending order; each block release-adds
//                     flags[st] when done (512 blocks per slice).
//  blocks [2048,3072): pass2 role — per-s 128x128x768 GEMM quadrant (64x64).
//                     Spins (relaxed, agent) until flags[st]==512, one
//                     acquire, then the debugged m97-style MFMA loop.
//  s-mapping keeps 16-consecutive-s (one 64B out line) on one XCD and s
//  ascending with launch order. flags==nullptr -> no sync (serial fallback).
// ---------------------------------------------------------------------------
__global__ __launch_bounds__(256) void fused(
    const float* __restrict__ x, const float* __restrict__ y,
    unsigned short* __restrict__ xb, unsigned short* __restrict__ yb,
    float* __restrict__ out, unsigned int* flags, int role_base) {
  __shared__ char smem[17408];
  const int b = (int)blockIdx.x + role_base;
  const int t = threadIdx.x;

  if (b < 2048) {
    // ------------------------------ pass1 ------------------------------
    const int st     = b >> 9;          // ascending completion order
    const int n      = (b >> 2) & 127;
    const int tensor = (b >> 1) & 1;
    const int ch2    = b & 1;           // c-half (0: c<384, 1: c>=384)

    const float*    src = tensor ? y  : x;
    unsigned short* dst = tensor ? yb : xb;
    float*          sqo = out + XY_ELEMS + tensor * XSQ_ELEMS;
    float*          tile0 = (float*)smem;   // [2][32*68] = 17408 B

    const int cl = t >> 4;               // 0..15 (load-side c row)
    const int s4 = (t & 15) * 4;         // 0..60 (load-side s offset)
    const int sl = t >> 2;               // 0..63 (store-side s row)
    const int cq = t & 3;                // 0..3  (store-side c group of 8)

    const float* srcn =
        src + (size_t)n * (C * S) + (size_t)(ch2 * 384) * S + st * 64;
    unsigned short* dstn =
        dst + ((size_t)(st * 64 + sl) * NB + n) * C + ch2 * 384;

    f32x4 acc = {0.f, 0.f, 0.f, 0.f};
    f32x4 c0r, c1r, n0r, n1r;

    c0r = __builtin_nontemporal_load(
        reinterpret_cast<const f32x4*>(srcn + (size_t)cl * S + s4));
    c1r = __builtin_nontemporal_load(
        reinterpret_cast<const f32x4*>(srcn + (size_t)(16 + cl) * S + s4));

#pragma unroll
    for (int ch = 0; ch < 12; ++ch) {
      float* tb = tile0 + (ch & 1) * 2176;

      if (ch < 11) {  // prefetch first (overlaps vmcnt stall on cur)
        const float* p0 = srcn + (size_t)((ch + 1) * 32 + cl) * S + s4;
        const float* p1 = srcn + (size_t)((ch + 1) * 32 + 16 + cl) * S + s4;
        n0r = __builtin_nontemporal_load(reinterpret_cast<const f32x4*>(p0));
        n1r = __builtin_nontemporal_load(reinterpret_cast<const f32x4*>(p1));
      }

      acc += c0r * c0r;
      acc += c1r * c1r;
      *reinterpret_cast<f32x4*>(
          &tb[cl * 68 + (s4 ^ (((cl >> 3) & 3) << 3))]) = c0r;
      *reinterpret_cast<f32x4*>(
          &tb[(16 + cl) * 68 + (s4 ^ ((((16 + cl) >> 3) & 3) << 3))]) = c1r;

      asm volatile("s_waitcnt lgkmcnt(0)" ::: "memory");
      __builtin_amdgcn_s_barrier();

      alignas(16) unsigned short u[8];
#pragma unroll
      for (int i = 0; i < 8; ++i) {
        int c_loc = cq * 8 + i;
        float f   = tb[c_loc * 68 + (sl ^ (cq << 3))];
        unsigned fu = __float_as_uint(f);
        unsigned r  = fu + 0x7fffu + ((fu >> 16) & 1u);  // RNE
        u[i] = (unsigned short)(r >> 16);
      }
      *reinterpret_cast<uint4*>(dstn + ch * 32 + cq * 8) =
          *reinterpret_cast<const uint4*>(u);

      c0r = n0r;
      c1r = n1r;
    }

    __syncthreads();   // drains vmcnt(0): all ws stores complete here
    float* part = tile0;  // reuse as [16][64]
#pragma unroll
    for (int j = 0; j < 4; ++j) part[cl * 64 + s4 + j] = acc[j];
    __syncthreads();
    if (t < 64) {
      float ssum = 0.f;
#pragma unroll
      for (int i = 0; i < 16; ++i) ssum += part[i * 64 + t];
      atomicAdd(&sqo[n * S + st * 64 + t], ssum * (1.0f / 768.0f));
    }
    if (flags && t == 0) {
      __hip_atomic_fetch_add(&flags[st], 1u, __ATOMIC_RELEASE,
                             __HIP_MEMORY_SCOPE_AGENT);
    }
  } else {
    // ------------------------------ pass2 ------------------------------
    const int j = b - 2048;             // 0..1023
    const int q = j >> 8;               // quadrant
    const int k = j & 255;
    // bijective; XCD = (2048+j)&7 = k&7 owns s-run [ (k&7)*16, +16 )
    const int s = ((k & 7) << 4) | ((k >> 3) & 15) | ((k >> 7) << 7);
    const int n0 = (q >> 1) * 64;
    const int m0 = (q & 1) * 64;

    if (flags) {
      if (t == 0) {
        const int st = s >> 6;
        while (__hip_atomic_load(&flags[st], __ATOMIC_RELAXED,
                                 __HIP_MEMORY_SCOPE_AGENT) < 512u)
          __builtin_amdgcn_s_sleep(16);
        (void)__hip_atomic_load(&flags[st], __ATOMIC_ACQUIRE,
                                __HIP_MEMORY_SCOPE_AGENT);
      }
      __syncthreads();
    }

    const unsigned short* A = xb + (size_t)s * (NB * C) + (size_t)n0 * C;
    const unsigned short* B = yb + (size_t)s * (NB * C) + (size_t)m0 * C;

    unsigned short* As = (unsigned short*)smem;           // 8192 B
    unsigned short* Bs = (unsigned short*)(smem + 8192);  // 8192 B

    const int lane = t & 63;
    const int w    = t >> 6;
    const int wn   = w >> 1;   // 0..1
    const int wm   = w & 1;    // 0..1

    f32x4 acc[2][2] = {};

    for (int k0 = 0; k0 < 12; ++k0) {
#pragma unroll
      for (int i = 0; i < 2; ++i) {
        int ci  = i * 256 + t;          // 0..511 = row*8 + jj
        int row = ci >> 3;
        int js  = (ci & 7) ^ (row & 7);
        const unsigned short* gpA = A + row * C + k0 * 64 + js * 8;
        const unsigned short* gpB = B + row * C + k0 * 64 + js * 8;
        __builtin_amdgcn_global_load_lds(
            (const AS1 unsigned int*)gpA,
            (AS3 unsigned int*)((char*)As + ci * 16), 16, 0, 0);
        __builtin_amdgcn_global_load_lds(
            (const AS1 unsigned int*)gpB,
            (AS3 unsigned int*)((char*)Bs + ci * 16), 16, 0, 0);
      }
      __syncthreads();

#pragma unroll
      for (int ks = 0; ks < 2; ++ks) {
        bf16x8 af[2], bfr[2];
        int jg = ks * 4 + (lane >> 4);
#pragma unroll
        for (int mi = 0; mi < 2; ++mi) {
          int row = wn * 32 + mi * 16 + (lane & 15);
          af[mi] = *reinterpret_cast<const bf16x8*>(
              (char*)As + row * 128 + ((jg ^ (row & 7)) * 16));
        }
#pragma unroll
        for (int nj = 0; nj < 2; ++nj) {
          int row = wm * 32 + nj * 16 + (lane & 15);
          bfr[nj] = *reinterpret_cast<const bf16x8*>(
              (char*)Bs + row * 128 + ((jg ^ (row & 7)) * 16));
        }
#pragma unroll
        for (int mi = 0; mi < 2; ++mi)
#pragma unroll
          for (int nj = 0; nj < 2; ++nj)
            acc[mi][nj] = __builtin_amdgcn_mfma_f32_16x16x32_bf16(
                af[mi], bfr[nj], acc[mi][nj], 0, 0, 0);
      }
      __syncthreads();
    }

    const float inv = 1.0f / 768.0f;
#pragma unroll
    for (int mi = 0; mi < 2; ++mi) {
#pragma unroll
      for (int nj = 0; nj < 2; ++nj) {
#pragma unroll
        for (int r = 0; r < 4; ++r) {
          int nn = n0 + wn * 32 + mi * 16 + (lane >> 4) * 4 + r;  // x index
          int mm = m0 + wm * 32 + nj * 16 + (lane & 15);          // y index
          out[((size_t)nn * NB + mm) * S + s] = acc[mi][nj][r] * inv;
        }
      }
    }
  }
}

extern "C" void kernel_launch(void* const* d_in, const int* in_sizes, int n_in,
                              void* d_out, int out_size, void* d_ws, size_t ws_size,
                              hipStream_t stream) {
  const float* x = (const float*)d_in[0];
  const float* y = (const float*)d_in[1];
  float* out = (float*)d_out;

  unsigned short* xb = (unsigned short*)d_ws;       // [256][128][768] bf16
  unsigned short* yb = xb + WS_TENSOR;

  size_t flags_off = 2 * WS_TENSOR * sizeof(unsigned short);  // 100,663,296
  bool overlap = ws_size >= flags_off + 64;
  unsigned int* flags =
      overlap ? (unsigned int*)((char*)d_ws + flags_off) : nullptr;

  // zero xx/yy (atomicAdd target) and the flags
  hipMemsetAsync(out + XY_ELEMS, 0, (size_t)2 * XSQ_ELEMS * sizeof(float),
                 stream);
  if (overlap) {
    hipMemsetAsync(flags, 0, 64, stream);
    fused<<<3072, 256, 0, stream>>>(x, y, xb, yb, out, flags, 0);
  } else {
    fused<<<2048, 256, 0, stream>>>(x, y, xb, yb, out, nullptr, 0);
    fused<<<1024, 256, 0, stream>>>(x, y, xb, yb, out, nullptr, 2048);
  }
}

// Round 5
// 101.453 us; speedup vs baseline: 2.4751x; 2.4751x over previous
//
#include <hip/hip_runtime.h>

#define AS1 __attribute__((address_space(1)))
#define AS3 __attribute__((address_space(3)))

typedef __bf16 bf16x8 __attribute__((ext_vector_type(8)));
typedef float f32x4 __attribute__((ext_vector_type(4)));

static constexpr int C = 768;
static constexpr int NB = 128;    // N1 == N2
static constexpr int S  = 256;    // W*H
static constexpr int XY_ELEMS  = NB * NB * S;  // 4194304
static constexpr int XSQ_ELEMS = NB * S;       // 32768
static constexpr size_t WS_TENSOR = (size_t)S * NB * C;

// ---------------------------------------------------------------------------
// Pass 1 (R3-verified, 63.5us): transpose [n][c][s] fp32 -> [s][n][c] bf16 +
// fused square-mean. grid 2048 = (tensor, n, s-tile 64, c-half 384).
// ---------------------------------------------------------------------------
__global__ __launch_bounds__(256) void pass1(const float* __restrict__ x,
                                             const float* __restrict__ y,
                                             unsigned short* __restrict__ xb,
                                             unsigned short* __restrict__ yb,
                                             float* __restrict__ out) {
  const int b      = blockIdx.x;
  const int tensor = b >> 10;
  const int local  = b & 1023;
  const int n      = local >> 3;
  const int st     = (local >> 1) & 3;
  const int ch2    = local & 1;

  const float*    src = tensor ? y  : x;
  unsigned short* dst = tensor ? yb : xb;
  float*          sqo = out + XY_ELEMS + tensor * XSQ_ELEMS;

  __shared__ float tile[2][32 * 68];

  const int t  = threadIdx.x;
  const int cl = t >> 4;
  const int s4 = (t & 15) * 4;
  const int sl = t >> 2;
  const int cq = t & 3;

  const float* srcn =
      src + (size_t)n * (C * S) + (size_t)(ch2 * 384) * S + st * 64;
  unsigned short* dstn =
      dst + ((size_t)(st * 64 + sl) * NB + n) * C + ch2 * 384;

  f32x4 acc = {0.f, 0.f, 0.f, 0.f};
  f32x4 c0r, c1r, n0r, n1r;

  c0r = __builtin_nontemporal_load(
      reinterpret_cast<const f32x4*>(srcn + (size_t)cl * S + s4));
  c1r = __builtin_nontemporal_load(
      reinterpret_cast<const f32x4*>(srcn + (size_t)(16 + cl) * S + s4));

#pragma unroll
  for (int ch = 0; ch < 12; ++ch) {
    float* tb = tile[ch & 1];

    if (ch < 11) {  // prefetch first (overlaps vmcnt stall on cur)
      const float* p0 = srcn + (size_t)((ch + 1) * 32 + cl) * S + s4;
      const float* p1 = srcn + (size_t)((ch + 1) * 32 + 16 + cl) * S + s4;
      n0r = __builtin_nontemporal_load(reinterpret_cast<const f32x4*>(p0));
      n1r = __builtin_nontemporal_load(reinterpret_cast<const f32x4*>(p1));
    }

    acc += c0r * c0r;
    acc += c1r * c1r;
    *reinterpret_cast<f32x4*>(
        &tb[cl * 68 + (s4 ^ (((cl >> 3) & 3) << 3))]) = c0r;
    *reinterpret_cast<f32x4*>(
        &tb[(16 + cl) * 68 + (s4 ^ ((((16 + cl) >> 3) & 3) << 3))]) = c1r;

    asm volatile("s_waitcnt lgkmcnt(0)" ::: "memory");
    __builtin_amdgcn_s_barrier();

    alignas(16) unsigned short u[8];
#pragma unroll
    for (int i = 0; i < 8; ++i) {
      int c_loc = cq * 8 + i;
      float f   = tb[c_loc * 68 + (sl ^ (cq << 3))];
      unsigned fu = __float_as_uint(f);
      unsigned r  = fu + 0x7fffu + ((fu >> 16) & 1u);  // RNE
      u[i] = (unsigned short)(r >> 16);
    }
    *reinterpret_cast<uint4*>(dstn + ch * 32 + cq * 8) =
        *reinterpret_cast<const uint4*>(u);

    c0r = n0r;
    c1r = n1r;
  }

  __syncthreads();
  float* part = &tile[0][0];
#pragma unroll
  for (int j = 0; j < 4; ++j) part[cl * 64 + s4 + j] = acc[j];
  __syncthreads();
  if (t < 64) {
    float ssum = 0.f;
#pragma unroll
    for (int i = 0; i < 16; ++i) ssum += part[i * 64 + t];
    atomicAdd(&sqo[n * S + st * 64 + t], ssum * (1.0f / 768.0f));
  }
}

// ---------------------------------------------------------------------------
// Pass 2: per s, C_s = (1/768) * A_s * B_s^T, full 128x128 tile (reads ws
// exactly once: 101 MB). Depth-3 staging pipeline: 4 LDS buffers (128 KB),
// raw s_barrier + counted vmcnt(16/8/0) so 3 batches of global_load_lds
// stay in flight across barriers (T3+T4) -> BW-bound, not latency-bound.
// grid 256, 256 threads (4 waves, 2x2 of 64x64). 1 block/CU (LDS-capped).
// ---------------------------------------------------------------------------
__global__ __launch_bounds__(256) void pass2(const unsigned short* __restrict__ xb,
                                             const unsigned short* __restrict__ yb,
                                             float* __restrict__ out) {
  const int bid = blockIdx.x;
  const int s = ((bid & 7) << 5) | (bid >> 3);  // XCD-aware, bijective

  const unsigned short* A = xb + (size_t)s * (NB * C);
  const unsigned short* B = yb + (size_t)s * (NB * C);

  __shared__ unsigned short As[4][128 * 64];   // 64 KB
  __shared__ unsigned short Bs[4][128 * 64];   // 64 KB

  const int t    = threadIdx.x;
  const int lane = t & 63;
  const int w    = t >> 6;
  const int wn   = w >> 1;
  const int wm   = w & 1;

  // per-thread staging addresses (4 x 16B chunks per operand per k-tile)
  const unsigned short* gA[4];
  const unsigned short* gB[4];
  int ldsoff[4];
#pragma unroll
  for (int i = 0; i < 4; ++i) {
    int ci  = i * 256 + t;          // row*8 + j
    int row = ci >> 3;
    int js  = (ci & 7) ^ (row & 7); // pre-swizzled source (rule 21)
    gA[i] = A + row * C + js * 8;
    gB[i] = B + row * C + js * 8;
    ldsoff[i] = ci * 16;
  }

#define STAGE(K0, BUF)                                                        \
  {                                                                           \
    _Pragma("unroll") for (int i = 0; i < 4; ++i) {                           \
      __builtin_amdgcn_global_load_lds(                                       \
          (const AS1 unsigned int*)(gA[i] + (K0)*64),                         \
          (AS3 unsigned int*)((char*)As[BUF] + ldsoff[i]), 16, 0, 0);         \
      __builtin_amdgcn_global_load_lds(                                       \
          (const AS1 unsigned int*)(gB[i] + (K0)*64),                         \
          (AS3 unsigned int*)((char*)Bs[BUF] + ldsoff[i]), 16, 0, 0);         \
    }                                                                         \
  }

  f32x4 acc[4][4] = {};

  // prologue: 3 tiles in flight
  STAGE(0, 0);
  STAGE(1, 1);
  STAGE(2, 2);
  asm volatile("s_waitcnt vmcnt(16)" ::: "memory");  // tile 0 landed
  __builtin_amdgcn_s_barrier();

#pragma unroll
  for (int k0 = 0; k0 < 12; ++k0) {
    if (k0 + 3 < 12) STAGE(k0 + 3, (k0 + 3) & 3);

    const char* Ab = (const char*)As[k0 & 3];
    const char* Bb = (const char*)Bs[k0 & 3];
#pragma unroll
    for (int ks = 0; ks < 2; ++ks) {
      bf16x8 af[4], bfr[4];
      int jg = ks * 4 + (lane >> 4);
#pragma unroll
      for (int mi = 0; mi < 4; ++mi) {
        int row = wn * 64 + mi * 16 + (lane & 15);
        af[mi] = *reinterpret_cast<const bf16x8*>(
            Ab + row * 128 + ((jg ^ (row & 7)) * 16));
      }
#pragma unroll
      for (int nj = 0; nj < 4; ++nj) {
        int row = wm * 64 + nj * 16 + (lane & 15);
        bfr[nj] = *reinterpret_cast<const bf16x8*>(
            Bb + row * 128 + ((jg ^ (row & 7)) * 16));
      }
#pragma unroll
      for (int mi = 0; mi < 4; ++mi)
#pragma unroll
        for (int nj = 0; nj < 4; ++nj)
          acc[mi][nj] = __builtin_amdgcn_mfma_f32_16x16x32_bf16(
              af[mi], bfr[nj], acc[mi][nj], 0, 0, 0);
    }

    // counted drain: only the next-needed batch, keep 2 batches in flight
    if (k0 < 9) {
      asm volatile("s_waitcnt vmcnt(16)" ::: "memory");
    } else if (k0 == 9) {
      asm volatile("s_waitcnt vmcnt(8)" ::: "memory");
    } else if (k0 == 10) {
      asm volatile("s_waitcnt vmcnt(0)" ::: "memory");
    }
    if (k0 < 11) __builtin_amdgcn_s_barrier();
  }
#undef STAGE

  // epilogue: C/D layout col=lane&15, row=(lane>>4)*4+reg (m89-verified).
  // Plain stores: 4B scatter at 1KB stride; the 16 blocks sharing each 64B
  // line are co-XCD (swizzle) and concurrent -> merge in that XCD's L2.
  const float inv = 1.0f / 768.0f;
#pragma unroll
  for (int mi = 0; mi < 4; ++mi) {
#pragma unroll
    for (int nj = 0; nj < 4; ++nj) {
#pragma unroll
      for (int r = 0; r < 4; ++r) {
        int nn = wn * 64 + mi * 16 + (lane >> 4) * 4 + r;  // x index
        int mm = wm * 64 + nj * 16 + (lane & 15);          // y index
        out[((size_t)nn * NB + mm) * S + s] = acc[mi][nj][r] * inv;
      }
    }
  }
}

extern "C" void kernel_launch(void* const* d_in, const int* in_sizes, int n_in,
                              void* d_out, int out_size, void* d_ws, size_t ws_size,
                              hipStream_t stream) {
  const float* x = (const float*)d_in[0];
  const float* y = (const float*)d_in[1];
  float* out = (float*)d_out;

  unsigned short* xb = (unsigned short*)d_ws;       // [256][128][768] bf16
  unsigned short* yb = xb + WS_TENSOR;

  // zero xx/yy (atomicAdd target)
  hipMemsetAsync(out + XY_ELEMS, 0, (size_t)2 * XSQ_ELEMS * sizeof(float),
                 stream);
  pass1<<<2048, 256, 0, stream>>>(x, y, xb, yb, out);
  pass2<<<256, 256, 0, stream>>>(xb, yb, out);
}

// Round 6
// 99.948 us; speedup vs baseline: 2.5124x; 1.0151x over previous
//
#include <hip/hip_runtime.h>

#define AS1 __attribute__((address_space(1)))
#define AS3 __attribute__((address_space(3)))

typedef __bf16 bf16x8 __attribute__((ext_vector_type(8)));
typedef float f32x4 __attribute__((ext_vector_type(4)));

static constexpr int C = 768;
static constexpr int NB = 128;    // N1 == N2
static constexpr int S  = 256;    // W*H
static constexpr int XY_ELEMS  = NB * NB * S;  // 4194304
static constexpr int XSQ_ELEMS = NB * S;       // 32768
static constexpr size_t WS_TENSOR = (size_t)S * NB * C;

// ---------------------------------------------------------------------------
// Pass 1 (frozen since R3; 63.5us, 3.2 TB/s, 0 bank conflicts): transpose
// [n][c][s] fp32 -> [s][n][c] bf16 + fused square-mean.
// grid 2048 = (tensor, n, s-tile 64, c-half 384).
// ---------------------------------------------------------------------------
__global__ __launch_bounds__(256) void pass1(const float* __restrict__ x,
                                             const float* __restrict__ y,
                                             unsigned short* __restrict__ xb,
                                             unsigned short* __restrict__ yb,
                                             float* __restrict__ out) {
  const int b      = blockIdx.x;
  const int tensor = b >> 10;
  const int local  = b & 1023;
  const int n      = local >> 3;
  const int st     = (local >> 1) & 3;
  const int ch2    = local & 1;

  const float*    src = tensor ? y  : x;
  unsigned short* dst = tensor ? yb : xb;
  float*          sqo = out + XY_ELEMS + tensor * XSQ_ELEMS;

  __shared__ float tile[2][32 * 68];

  const int t  = threadIdx.x;
  const int cl = t >> 4;
  const int s4 = (t & 15) * 4;
  const int sl = t >> 2;
  const int cq = t & 3;

  const float* srcn =
      src + (size_t)n * (C * S) + (size_t)(ch2 * 384) * S + st * 64;
  unsigned short* dstn =
      dst + ((size_t)(st * 64 + sl) * NB + n) * C + ch2 * 384;

  f32x4 acc = {0.f, 0.f, 0.f, 0.f};
  f32x4 c0r, c1r, n0r, n1r;

  c0r = __builtin_nontemporal_load(
      reinterpret_cast<const f32x4*>(srcn + (size_t)cl * S + s4));
  c1r = __builtin_nontemporal_load(
      reinterpret_cast<const f32x4*>(srcn + (size_t)(16 + cl) * S + s4));

#pragma unroll
  for (int ch = 0; ch < 12; ++ch) {
    float* tb = tile[ch & 1];

    if (ch < 11) {  // prefetch first (overlaps vmcnt stall on cur)
      const float* p0 = srcn + (size_t)((ch + 1) * 32 + cl) * S + s4;
      const float* p1 = srcn + (size_t)((ch + 1) * 32 + 16 + cl) * S + s4;
      n0r = __builtin_nontemporal_load(reinterpret_cast<const f32x4*>(p0));
      n1r = __builtin_nontemporal_load(reinterpret_cast<const f32x4*>(p1));
    }

    acc += c0r * c0r;
    acc += c1r * c1r;
    *reinterpret_cast<f32x4*>(
        &tb[cl * 68 + (s4 ^ (((cl >> 3) & 3) << 3))]) = c0r;
    *reinterpret_cast<f32x4*>(
        &tb[(16 + cl) * 68 + (s4 ^ ((((16 + cl) >> 3) & 3) << 3))]) = c1r;

    asm volatile("s_waitcnt lgkmcnt(0)" ::: "memory");
    __builtin_amdgcn_s_barrier();

    alignas(16) unsigned short u[8];
#pragma unroll
    for (int i = 0; i < 8; ++i) {
      int c_loc = cq * 8 + i;
      float f   = tb[c_loc * 68 + (sl ^ (cq << 3))];
      unsigned fu = __float_as_uint(f);
      unsigned r  = fu + 0x7fffu + ((fu >> 16) & 1u);  // RNE
      u[i] = (unsigned short)(r >> 16);
    }
    *reinterpret_cast<uint4*>(dstn + ch * 32 + cq * 8) =
        *reinterpret_cast<const uint4*>(u);

    c0r = n0r;
    c1r = n1r;
  }

  __syncthreads();
  float* part = &tile[0][0];
#pragma unroll
  for (int j = 0; j < 4; ++j) part[cl * 64 + s4 + j] = acc[j];
  __syncthreads();
  if (t < 64) {
    float ssum = 0.f;
#pragma unroll
    for (int i = 0; i < 16; ++i) ssum += part[i * 64 + t];
    atomicAdd(&sqo[n * S + st * 64 + t], ssum * (1.0f / 768.0f));
  }
}

// ---------------------------------------------------------------------------
// Pass 2: n-split halves. Block = (s, half): A = 64 x-rows, B = full 128
// y-rows, full K=768. grid 512, LDS 48 KB (2-deep dbuf) -> 3 blocks/CU,
// 12 waves/CU. Counted vmcnt(6) = exactly one k-tile in flight (T4).
// The two same-s blocks are dispatch-adjacent + co-XCD -> duplicate B read
// hits L2 (196 KB << 4 MB). Out rows disjoint -> no atomics.
// ---------------------------------------------------------------------------
__global__ __launch_bounds__(256) void pass2(const unsigned short* __restrict__ xb,
                                             const unsigned short* __restrict__ yb,
                                             float* __restrict__ out) {
  const int b    = blockIdx.x;
  const int xcd  = b & 7;
  const int idx  = b >> 3;            // 0..63
  const int s    = xcd * 32 + (idx >> 1);
  const int half = idx & 1;

  const unsigned short* A = xb + (size_t)s * (NB * C) + (size_t)half * 64 * C;
  const unsigned short* B = yb + (size_t)s * (NB * C);

  __shared__ unsigned short As[2][64 * 64];    // 2 x 8 KB
  __shared__ unsigned short Bs[2][128 * 64];   // 2 x 16 KB

  const int t    = threadIdx.x;
  const int lane = t & 63;
  const int w    = t >> 6;
  const int wn   = w >> 1;   // 0..1: A-row 32-group
  const int wm   = w & 1;    // 0..1: B-row 64-group

  // staging addresses: A 512 chunks of 16B (2/thread), B 1024 (4/thread);
  // source pre-swizzled js = j ^ (row&7), LDS linear (rule 21).
  const unsigned short* gA[2];
  int loA[2];
#pragma unroll
  for (int i = 0; i < 2; ++i) {
    int ci  = i * 256 + t;
    int row = ci >> 3;
    int js  = (ci & 7) ^ (row & 7);
    gA[i]  = A + row * C + js * 8;
    loA[i] = ci * 16;
  }
  const unsigned short* gB[4];
  int loB[4];
#pragma unroll
  for (int i = 0; i < 4; ++i) {
    int ci  = i * 256 + t;
    int row = ci >> 3;
    int js  = (ci & 7) ^ (row & 7);
    gB[i]  = B + row * C + js * 8;
    loB[i] = ci * 16;
  }

#define STAGE(K0, BUF)                                                        \
  {                                                                           \
    _Pragma("unroll") for (int i = 0; i < 2; ++i)                             \
        __builtin_amdgcn_global_load_lds(                                     \
            (const AS1 unsigned int*)(gA[i] + (K0)*64),                       \
            (AS3 unsigned int*)((char*)As[BUF] + loA[i]), 16, 0, 0);          \
    _Pragma("unroll") for (int i = 0; i < 4; ++i)                             \
        __builtin_amdgcn_global_load_lds(                                     \
            (const AS1 unsigned int*)(gB[i] + (K0)*64),                       \
            (AS3 unsigned int*)((char*)Bs[BUF] + loB[i]), 16, 0, 0);          \
  }

  f32x4 acc[2][4] = {};

  STAGE(0, 0);

#pragma unroll
  for (int k0 = 0; k0 < 12; ++k0) {
    if (k0 < 11) STAGE(k0 + 1, (k0 + 1) & 1);

    // wait for tile k0 only (6 newer loads stay in flight)
    if (k0 < 11) {
      asm volatile("s_waitcnt vmcnt(6)" ::: "memory");
    } else {
      asm volatile("s_waitcnt vmcnt(0)" ::: "memory");
    }
    __builtin_amdgcn_s_barrier();

    const char* Ab = (const char*)As[k0 & 1];
    const char* Bb = (const char*)Bs[k0 & 1];
#pragma unroll
    for (int ks = 0; ks < 2; ++ks) {
      bf16x8 af[2], bfr[4];
      int jg = ks * 4 + (lane >> 4);
#pragma unroll
      for (int mi = 0; mi < 2; ++mi) {
        int row = wn * 32 + mi * 16 + (lane & 15);
        af[mi] = *reinterpret_cast<const bf16x8*>(
            Ab + row * 128 + ((jg ^ (row & 7)) * 16));
      }
#pragma unroll
      for (int nj = 0; nj < 4; ++nj) {
        int row = wm * 64 + nj * 16 + (lane & 15);
        bfr[nj] = *reinterpret_cast<const bf16x8*>(
            Bb + row * 128 + ((jg ^ (row & 7)) * 16));
      }
#pragma unroll
      for (int mi = 0; mi < 2; ++mi)
#pragma unroll
        for (int nj = 0; nj < 4; ++nj)
          acc[mi][nj] = __builtin_amdgcn_mfma_f32_16x16x32_bf16(
              af[mi], bfr[nj], acc[mi][nj], 0, 0, 0);
    }

    // all waves done reading buf (k0&1) before iter k0+1 restages it
    if (k0 < 11) __builtin_amdgcn_s_barrier();
  }
#undef STAGE

  // epilogue: C/D layout col=lane&15, row=(lane>>4)*4+reg (m89-verified)
  const float inv = 1.0f / 768.0f;
#pragma unroll
  for (int mi = 0; mi < 2; ++mi) {
#pragma unroll
    for (int nj = 0; nj < 4; ++nj) {
#pragma unroll
      for (int r = 0; r < 4; ++r) {
        int nn = half * 64 + wn * 32 + mi * 16 + (lane >> 4) * 4 + r;  // x idx
        int mm = wm * 64 + nj * 16 + (lane & 15);                      // y idx
        out[((size_t)nn * NB + mm) * S + s] = acc[mi][nj][r] * inv;
      }
    }
  }
}

extern "C" void kernel_launch(void* const* d_in, const int* in_sizes, int n_in,
                              void* d_out, int out_size, void* d_ws, size_t ws_size,
                              hipStream_t stream) {
  const float* x = (const float*)d_in[0];
  const float* y = (const float*)d_in[1];
  float* out = (float*)d_out;

  unsigned short* xb = (unsigned short*)d_ws;       // [256][128][768] bf16
  unsigned short* yb = xb + WS_TENSOR;

  // zero xx/yy (atomicAdd target)
  hipMemsetAsync(out + XY_ELEMS, 0, (size_t)2 * XSQ_ELEMS * sizeof(float),
                 stream);
  pass1<<<2048, 256, 0, stream>>>(x, y, xb, yb, out);
  pass2<<<512, 256, 0, stream>>>(xb, yb, out);
}

// Round 7
// 92.566 us; speedup vs baseline: 2.7128x; 1.0797x over previous
//
#include <hip/hip_runtime.h>

#define AS1 __attribute__((address_space(1)))
#define AS3 __attribute__((address_space(3)))

typedef float f32x4 __attribute__((ext_vector_type(4)));
typedef long lx2 __attribute__((ext_vector_type(2)));

static constexpr int C = 768;
static constexpr int NB = 128;    // N1 == N2
static constexpr int S  = 256;    // W*H
static constexpr int XY_ELEMS  = NB * NB * S;  // 4194304
static constexpr int XSQ_ELEMS = NB * S;       // 32768
static constexpr size_t WS_TENSOR_B = (size_t)S * NB * C;  // bytes (fp8)

// ---------------------------------------------------------------------------
// Pass 1: transpose [n][c][s] fp32 -> [s][n][c] fp8(e4m3) + fused square-mean
// (squares from fp32, exact). grid 2048 = (tensor, n, s-tile 64, c-half 384).
// ws c-layout is PRE-PERMUTED per 64-c k-tile so pass2 stages linearly and
// reads both K=32 fragments with one swizzled ds_read_b128:
//   slot(u) = 2*((u&3)^sn) + (u>>2),  u = 8B unit (c>>3)&7,  sn = (n>>1)&3.
// ---------------------------------------------------------------------------
__global__ __launch_bounds__(256) void pass1(const float* __restrict__ x,
                                             const float* __restrict__ y,
                                             unsigned char* __restrict__ xb,
                                             unsigned char* __restrict__ yb,
                                             float* __restrict__ out) {
  const int b      = blockIdx.x;
  const int tensor = b >> 10;
  const int local  = b & 1023;
  const int n      = local >> 3;
  const int st     = (local >> 1) & 3;
  const int ch2    = local & 1;

  const float*   src = tensor ? y  : x;
  unsigned char* dst = tensor ? yb : xb;
  float*         sqo = out + XY_ELEMS + tensor * XSQ_ELEMS;

  __shared__ float tile[2][32 * 68];

  const int t  = threadIdx.x;
  const int cl = t >> 4;
  const int s4 = (t & 15) * 4;
  const int sl = t >> 2;
  const int cq = t & 3;
  const int sn = (n >> 1) & 3;

  const float* srcn =
      src + (size_t)n * (C * S) + (size_t)(ch2 * 384) * S + st * 64;
  unsigned char* dstrow = dst + ((size_t)(st * 64 + sl) * NB + n) * C;

  f32x4 acc = {0.f, 0.f, 0.f, 0.f};
  f32x4 c0r, c1r, n0r, n1r;

  c0r = __builtin_nontemporal_load(
      reinterpret_cast<const f32x4*>(srcn + (size_t)cl * S + s4));
  c1r = __builtin_nontemporal_load(
      reinterpret_cast<const f32x4*>(srcn + (size_t)(16 + cl) * S + s4));

#pragma unroll
  for (int ch = 0; ch < 12; ++ch) {
    float* tb = tile[ch & 1];

    if (ch < 11) {  // prefetch first (overlaps vmcnt stall on cur)
      const float* p0 = srcn + (size_t)((ch + 1) * 32 + cl) * S + s4;
      const float* p1 = srcn + (size_t)((ch + 1) * 32 + 16 + cl) * S + s4;
      n0r = __builtin_nontemporal_load(reinterpret_cast<const f32x4*>(p0));
      n1r = __builtin_nontemporal_load(reinterpret_cast<const f32x4*>(p1));
    }

    acc += c0r * c0r;
    acc += c1r * c1r;
    *reinterpret_cast<f32x4*>(
        &tb[cl * 68 + (s4 ^ (((cl >> 3) & 3) << 3))]) = c0r;
    *reinterpret_cast<f32x4*>(
        &tb[(16 + cl) * 68 + (s4 ^ ((((16 + cl) >> 3) & 3) << 3))]) = c1r;

    asm volatile("s_waitcnt lgkmcnt(0)" ::: "memory");
    __builtin_amdgcn_s_barrier();

    // transposed read of 8 floats (c = ch*32 + cq*8 ..+8) -> fp8 e4m3 pack
    float f[8];
#pragma unroll
    for (int i = 0; i < 8; ++i)
      f[i] = tb[(cq * 8 + i) * 68 + (sl ^ (cq << 3))];
    int lo = __builtin_amdgcn_cvt_pk_fp8_f32(f[0], f[1], 0, false);
    lo     = __builtin_amdgcn_cvt_pk_fp8_f32(f[2], f[3], lo, true);
    int hi = __builtin_amdgcn_cvt_pk_fp8_f32(f[4], f[5], 0, false);
    hi     = __builtin_amdgcn_cvt_pk_fp8_f32(f[6], f[7], hi, true);
    uint2 v8 = make_uint2((unsigned)lo, (unsigned)hi);

    // permuted store: u = (ch&1)*4 + cq; slot = 2*(cq^sn) + (ch&1)
    const int kt   = ch2 * 6 + (ch >> 1);
    const int slot = 2 * (cq ^ sn) + (ch & 1);
    *reinterpret_cast<uint2*>(dstrow + kt * 64 + slot * 8) = v8;

    c0r = n0r;
    c1r = n1r;
  }

  __syncthreads();
  float* part = &tile[0][0];
#pragma unroll
  for (int j = 0; j < 4; ++j) part[cl * 64 + s4 + j] = acc[j];
  __syncthreads();
  if (t < 64) {
    float ssum = 0.f;
#pragma unroll
    for (int i = 0; i < 16; ++i) ssum += part[i * 64 + t];
    atomicAdd(&sqo[n * S + st * 64 + t], ssum * (1.0f / 768.0f));
  }
}

// ---------------------------------------------------------------------------
// Pass 2: per s, C_s = (1/768) * A_s * B_s^T, fp8 e4m3, full 128x128 tile
// (reads ws exactly once: 49 MB total). BK=64, 2-deep dbuf (32 KB LDS),
// counted vmcnt(4). One ds_read_b128 per row per k-tile yields BOTH K=32
// fragments (ws layout pre-permuted by pass1); 16B-granule XOR swizzle
// ((row>>1)&3) -> 2-way bank aliasing (free).
// grid 256 x 256 threads (4 waves, 2x2 of 64x64).
// ---------------------------------------------------------------------------
__global__ __launch_bounds__(256) void pass2(const unsigned char* __restrict__ xb,
                                             const unsigned char* __restrict__ yb,
                                             float* __restrict__ out) {
  const int bid = blockIdx.x;
  const int s = ((bid & 7) << 5) | (bid >> 3);  // XCD-aware, bijective

  const unsigned char* A = xb + (size_t)s * (NB * C);
  const unsigned char* B = yb + (size_t)s * (NB * C);

  __shared__ unsigned char As[2][128 * 64];   // 2 x 8 KB
  __shared__ unsigned char Bs[2][128 * 64];   // 2 x 8 KB

  const int t    = threadIdx.x;
  const int lane = t & 63;
  const int w    = t >> 6;
  const int wn   = w >> 1;
  const int wm   = w & 1;

  // staging: 512 x 16B chunks per operand per k-tile, 2/thread, linear both
  // sides (swizzle baked into ws by pass1)
  const unsigned char* gA[2];
  const unsigned char* gB[2];
  int lo16[2];
#pragma unroll
  for (int i = 0; i < 2; ++i) {
    int ci  = i * 256 + t;          // row*4 + j16
    int row = ci >> 2;
    int j16 = ci & 3;
    gA[i]   = A + row * C + j16 * 16;
    gB[i]   = B + row * C + j16 * 16;
    lo16[i] = ci * 16;
  }

#define STAGE(K0, BUF)                                                        \
  {                                                                           \
    _Pragma("unroll") for (int i = 0; i < 2; ++i) {                           \
      __builtin_amdgcn_global_load_lds(                                       \
          (const AS1 unsigned int*)(gA[i] + (K0)*64),                         \
          (AS3 unsigned int*)((char*)As[BUF] + lo16[i]), 16, 0, 0);           \
      __builtin_amdgcn_global_load_lds(                                       \
          (const AS1 unsigned int*)(gB[i] + (K0)*64),                         \
          (AS3 unsigned int*)((char*)Bs[BUF] + lo16[i]), 16, 0, 0);           \
    }                                                                         \
  }

  f32x4 acc[4][4] = {};

  STAGE(0, 0);

#pragma unroll
  for (int k0 = 0; k0 < 12; ++k0) {
    if (k0 < 11) STAGE(k0 + 1, (k0 + 1) & 1);

    if (k0 < 11) {
      asm volatile("s_waitcnt vmcnt(4)" ::: "memory");  // tile k0 landed
    } else {
      asm volatile("s_waitcnt vmcnt(0)" ::: "memory");
    }
    __builtin_amdgcn_s_barrier();

    const char* Ab = (const char*)As[k0 & 1];
    const char* Bb = (const char*)Bs[k0 & 1];

    lx2 av[4], bv[4];
    const int q = lane >> 4;
#pragma unroll
    for (int mi = 0; mi < 4; ++mi) {
      int row = wn * 64 + mi * 16 + (lane & 15);
      av[mi] = *reinterpret_cast<const lx2*>(
          Ab + row * 64 + ((q ^ ((row >> 1) & 3)) * 16));
    }
#pragma unroll
    for (int nj = 0; nj < 4; ++nj) {
      int row = wm * 64 + nj * 16 + (lane & 15);
      bv[nj] = *reinterpret_cast<const lx2*>(
          Bb + row * 64 + ((q ^ ((row >> 1) & 3)) * 16));
    }
#pragma unroll
    for (int mi = 0; mi < 4; ++mi)
#pragma unroll
      for (int nj = 0; nj < 4; ++nj) {
        acc[mi][nj] = __builtin_amdgcn_mfma_f32_16x16x32_fp8_fp8(
            av[mi][0], bv[nj][0], acc[mi][nj], 0, 0, 0);
        acc[mi][nj] = __builtin_amdgcn_mfma_f32_16x16x32_fp8_fp8(
            av[mi][1], bv[nj][1], acc[mi][nj], 0, 0, 0);
      }

    if (k0 < 11) __builtin_amdgcn_s_barrier();  // buf safe to restage
  }
#undef STAGE

  // epilogue: C/D layout col=lane&15, row=(lane>>4)*4+reg (shape-determined,
  // dtype-independent per m121-m128)
  const float inv = 1.0f / 768.0f;
#pragma unroll
  for (int mi = 0; mi < 4; ++mi) {
#pragma unroll
    for (int nj = 0; nj < 4; ++nj) {
#pragma unroll
      for (int r = 0; r < 4; ++r) {
        int nn = wn * 64 + mi * 16 + (lane >> 4) * 4 + r;  // x index
        int mm = wm * 64 + nj * 16 + (lane & 15);          // y index
        out[((size_t)nn * NB + mm) * S + s] = acc[mi][nj][r] * inv;
      }
    }
  }
}

extern "C" void kernel_launch(void* const* d_in, const int* in_sizes, int n_in,
                              void* d_out, int out_size, void* d_ws, size_t ws_size,
                              hipStream_t stream) {
  const float* x = (const float*)d_in[0];
  const float* y = (const float*)d_in[1];
  float* out = (float*)d_out;

  unsigned char* xb = (unsigned char*)d_ws;       // [256][128][768] fp8
  unsigned char* yb = xb + WS_TENSOR_B;

  // zero xx/yy (atomicAdd target)
  hipMemsetAsync(out + XY_ELEMS, 0, (size_t)2 * XSQ_ELEMS * sizeof(float),
                 stream);
  pass1<<<2048, 256, 0, stream>>>(x, y, xb, yb, out);
  pass2<<<256, 256, 0, stream>>>(xb, yb, out);
}

// Round 8
// 84.037 us; speedup vs baseline: 2.9881x; 1.1015x over previous
//
#include <hip/hip_runtime.h>

#define AS1 __attribute__((address_space(1)))
#define AS3 __attribute__((address_space(3)))

typedef float f32x4 __attribute__((ext_vector_type(4)));
typedef long lx2 __attribute__((ext_vector_type(2)));

static constexpr int C = 768;
static constexpr int NB = 128;    // N1 == N2
static constexpr int S  = 256;    // W*H
static constexpr int XY_ELEMS  = NB * NB * S;  // 4194304
static constexpr int XSQ_ELEMS = NB * S;       // 32768
static constexpr size_t WS_TENSOR_B = (size_t)S * NB * C;  // bytes (fp8)

// ---------------------------------------------------------------------------
// Pass 1 (frozen, R7-verified 58.5us): transpose [n][c][s] fp32 -> [s][n][c]
// fp8 e4m3 + fused square-mean (squares from fp32, exact).
// ws c-layout PRE-PERMUTED per 64-c k-tile (slot = 2*((u&3)^sn) + (u>>2),
// sn=(n>>1)&3) so pass2 stages linearly and swizzle-reads b128.
// ---------------------------------------------------------------------------
__global__ __launch_bounds__(256) void pass1(const float* __restrict__ x,
                                             const float* __restrict__ y,
                                             unsigned char* __restrict__ xb,
                                             unsigned char* __restrict__ yb,
                                             float* __restrict__ out) {
  const int b      = blockIdx.x;
  const int tensor = b >> 10;
  const int local  = b & 1023;
  const int n      = local >> 3;
  const int st     = (local >> 1) & 3;
  const int ch2    = local & 1;

  const float*   src = tensor ? y  : x;
  unsigned char* dst = tensor ? yb : xb;
  float*         sqo = out + XY_ELEMS + tensor * XSQ_ELEMS;

  __shared__ float tile[2][32 * 68];

  const int t  = threadIdx.x;
  const int cl = t >> 4;
  const int s4 = (t & 15) * 4;
  const int sl = t >> 2;
  const int cq = t & 3;
  const int sn = (n >> 1) & 3;

  const float* srcn =
      src + (size_t)n * (C * S) + (size_t)(ch2 * 384) * S + st * 64;
  unsigned char* dstrow = dst + ((size_t)(st * 64 + sl) * NB + n) * C;

  f32x4 acc = {0.f, 0.f, 0.f, 0.f};
  f32x4 c0r, c1r, n0r, n1r;

  c0r = __builtin_nontemporal_load(
      reinterpret_cast<const f32x4*>(srcn + (size_t)cl * S + s4));
  c1r = __builtin_nontemporal_load(
      reinterpret_cast<const f32x4*>(srcn + (size_t)(16 + cl) * S + s4));

#pragma unroll
  for (int ch = 0; ch < 12; ++ch) {
    float* tb = tile[ch & 1];

    if (ch < 11) {  // prefetch first (overlaps vmcnt stall on cur)
      const float* p0 = srcn + (size_t)((ch + 1) * 32 + cl) * S + s4;
      const float* p1 = srcn + (size_t)((ch + 1) * 32 + 16 + cl) * S + s4;
      n0r = __builtin_nontemporal_load(reinterpret_cast<const f32x4*>(p0));
      n1r = __builtin_nontemporal_load(reinterpret_cast<const f32x4*>(p1));
    }

    acc += c0r * c0r;
    acc += c1r * c1r;
    *reinterpret_cast<f32x4*>(
        &tb[cl * 68 + (s4 ^ (((cl >> 3) & 3) << 3))]) = c0r;
    *reinterpret_cast<f32x4*>(
        &tb[(16 + cl) * 68 + (s4 ^ ((((16 + cl) >> 3) & 3) << 3))]) = c1r;

    asm volatile("s_waitcnt lgkmcnt(0)" ::: "memory");
    __builtin_amdgcn_s_barrier();

    float f[8];
#pragma unroll
    for (int i = 0; i < 8; ++i)
      f[i] = tb[(cq * 8 + i) * 68 + (sl ^ (cq << 3))];
    int lo = __builtin_amdgcn_cvt_pk_fp8_f32(f[0], f[1], 0, false);
    lo     = __builtin_amdgcn_cvt_pk_fp8_f32(f[2], f[3], lo, true);
    int hi = __builtin_amdgcn_cvt_pk_fp8_f32(f[4], f[5], 0, false);
    hi     = __builtin_amdgcn_cvt_pk_fp8_f32(f[6], f[7], hi, true);
    uint2 v8 = make_uint2((unsigned)lo, (unsigned)hi);

    const int kt   = ch2 * 6 + (ch >> 1);
    const int slot = 2 * (cq ^ sn) + (ch & 1);
    *reinterpret_cast<uint2*>(dstrow + kt * 64 + slot * 8) = v8;

    c0r = n0r;
    c1r = n1r;
  }

  __syncthreads();
  float* part = &tile[0][0];
#pragma unroll
  for (int j = 0; j < 4; ++j) part[cl * 64 + s4 + j] = acc[j];
  __syncthreads();
  if (t < 64) {
    float ssum = 0.f;
#pragma unroll
    for (int i = 0; i < 16; ++i) ssum += part[i * 64 + t];
    atomicAdd(&sqo[n * S + st * 64 + t], ssum * (1.0f / 768.0f));
  }
}

// ---------------------------------------------------------------------------
// Pass 2: per s, fp8 e4m3 128x128x768 GEMM (loop frozen from R7). Epilogue
// now writes CONTIGUOUS fp32 ws2[s][m][n]: 16B dwordx4 per acc quad, 16 full
// 64B lines per wave-instruction (replaces the 4B/1KB-stride out scatter).
// ---------------------------------------------------------------------------
__global__ __launch_bounds__(256) void pass2(const unsigned char* __restrict__ xb,
                                             const unsigned char* __restrict__ yb,
                                             float* __restrict__ ws2) {
  const int bid = blockIdx.x;
  const int s = ((bid & 7) << 5) | (bid >> 3);  // XCD-aware, bijective

  const unsigned char* A = xb + (size_t)s * (NB * C);
  const unsigned char* B = yb + (size_t)s * (NB * C);

  __shared__ unsigned char As[2][128 * 64];
  __shared__ unsigned char Bs[2][128 * 64];

  const int t    = threadIdx.x;
  const int lane = t & 63;
  const int w    = t >> 6;
  const int wn   = w >> 1;
  const int wm   = w & 1;

  const unsigned char* gA[2];
  const unsigned char* gB[2];
  int lo16[2];
#pragma unroll
  for (int i = 0; i < 2; ++i) {
    int ci  = i * 256 + t;
    int row = ci >> 2;
    int j16 = ci & 3;
    gA[i]   = A + row * C + j16 * 16;
    gB[i]   = B + row * C + j16 * 16;
    lo16[i] = ci * 16;
  }

#define STAGE(K0, BUF)                                                        \
  {                                                                           \
    _Pragma("unroll") for (int i = 0; i < 2; ++i) {                           \
      __builtin_amdgcn_global_load_lds(                                       \
          (const AS1 unsigned int*)(gA[i] + (K0)*64),                         \
          (AS3 unsigned int*)((char*)As[BUF] + lo16[i]), 16, 0, 0);           \
      __builtin_amdgcn_global_load_lds(                                       \
          (const AS1 unsigned int*)(gB[i] + (K0)*64),                         \
          (AS3 unsigned int*)((char*)Bs[BUF] + lo16[i]), 16, 0, 0);           \
    }                                                                         \
  }

  f32x4 acc[4][4] = {};

  STAGE(0, 0);

#pragma unroll
  for (int k0 = 0; k0 < 12; ++k0) {
    if (k0 < 11) STAGE(k0 + 1, (k0 + 1) & 1);

    if (k0 < 11) {
      asm volatile("s_waitcnt vmcnt(4)" ::: "memory");
    } else {
      asm volatile("s_waitcnt vmcnt(0)" ::: "memory");
    }
    __builtin_amdgcn_s_barrier();

    const char* Ab = (const char*)As[k0 & 1];
    const char* Bb = (const char*)Bs[k0 & 1];

    lx2 av[4], bv[4];
    const int q = lane >> 4;
#pragma unroll
    for (int mi = 0; mi < 4; ++mi) {
      int row = wn * 64 + mi * 16 + (lane & 15);
      av[mi] = *reinterpret_cast<const lx2*>(
          Ab + row * 64 + ((q ^ ((row >> 1) & 3)) * 16));
    }
#pragma unroll
    for (int nj = 0; nj < 4; ++nj) {
      int row = wm * 64 + nj * 16 + (lane & 15);
      bv[nj] = *reinterpret_cast<const lx2*>(
          Bb + row * 64 + ((q ^ ((row >> 1) & 3)) * 16));
    }
#pragma unroll
    for (int mi = 0; mi < 4; ++mi)
#pragma unroll
      for (int nj = 0; nj < 4; ++nj) {
        acc[mi][nj] = __builtin_amdgcn_mfma_f32_16x16x32_fp8_fp8(
            av[mi][0], bv[nj][0], acc[mi][nj], 0, 0, 0);
        acc[mi][nj] = __builtin_amdgcn_mfma_f32_16x16x32_fp8_fp8(
            av[mi][1], bv[nj][1], acc[mi][nj], 0, 0, 0);
      }

    if (k0 < 11) __builtin_amdgcn_s_barrier();
  }
#undef STAGE

  // epilogue: acc[mi][nj][r] has n = wn*64+mi*16+(lane>>4)*4+r (contiguous in
  // r), m = wm*64+nj*16+(lane&15). Store 16B per quad to ws2[s][m][n]:
  // lanes {L, L+16, L+32, L+48} complete each 64B line.
  const float inv = 1.0f / 768.0f;
  float* w2 = ws2 + (size_t)s * (NB * NB);
#pragma unroll
  for (int mi = 0; mi < 4; ++mi) {
#pragma unroll
    for (int nj = 0; nj < 4; ++nj) {
      f32x4 v = acc[mi][nj] * inv;
      int mm = wm * 64 + nj * 16 + (lane & 15);
      int nn = wn * 64 + mi * 16 + (lane >> 4) * 4;
      *reinterpret_cast<f32x4*>(w2 + (size_t)mm * NB + nn) = v;
    }
  }
}

// ---------------------------------------------------------------------------
// Pass 3: transpose ws2[s][m][n] -> out[n][m][s]. Block = (m, s-tile 64,
// n-tile 64): both global sides coalesced in 256B runs; LDS 64x64 tile with
// 16B-chunk XOR swizzle (chunk ^= (s>>2)&15) -> <=2-way conflicts.
// Nontemporal final store (out is not re-read; keep x/y L3-resident).
// ---------------------------------------------------------------------------
__global__ __launch_bounds__(256) void pass3(const float* __restrict__ ws2,
                                             float* __restrict__ out) {
  const int bid = blockIdx.x;        // 1024 blocks
  const int m   = bid & 127;
  const int st  = (bid >> 7) & 3;
  const int nt  = bid >> 9;          // 0..1
  const int t   = threadIdx.x;
  const int l16 = t & 15;
  const int hi4 = t >> 4;

  __shared__ float tile[64 * 64];    // swizzled [s][nchunk^((s>>2)&15)][4]

  const float* src = ws2 + ((size_t)(st * 64) * NB + m) * NB + nt * 64;
#pragma unroll
  for (int i = 0; i < 4; ++i) {
    int s_local = hi4 + 16 * i;
    f32x4 v = *reinterpret_cast<const f32x4*>(
        src + (size_t)s_local * (NB * NB) + l16 * 4);
    int chunk = l16 ^ ((s_local >> 2) & 15);
    *reinterpret_cast<f32x4*>(&tile[s_local * 64 + chunk * 4]) = v;
  }
  __syncthreads();

  float* dst = out + ((size_t)(nt * 64) * NB + m) * S + st * 64;
#pragma unroll
  for (int i = 0; i < 4; ++i) {
    int n_local = hi4 + 16 * i;
    int cb      = (n_local >> 2) & 15;   // n-chunk
    int ne      = n_local & 3;           // elem within chunk
    int s4      = l16 * 4;
    f32x4 v;
#pragma unroll
    for (int j = 0; j < 4; ++j) {
      int ss = s4 + j;
      v[j] = tile[ss * 64 + ((cb ^ ((ss >> 2) & 15)) << 2) + ne];
    }
    __builtin_nontemporal_store(
        v, reinterpret_cast<f32x4*>(dst + (size_t)n_local * (NB * S) + s4));
  }
}

extern "C" void kernel_launch(void* const* d_in, const int* in_sizes, int n_in,
                              void* d_out, int out_size, void* d_ws, size_t ws_size,
                              hipStream_t stream) {
  const float* x = (const float*)d_in[0];
  const float* y = (const float*)d_in[1];
  float* out = (float*)d_out;

  unsigned char* xb = (unsigned char*)d_ws;       // [256][128][768] fp8
  unsigned char* yb = xb + WS_TENSOR_B;
  float* ws2 = (float*)((char*)d_ws + 2 * WS_TENSOR_B);  // [256][128][128] f32

  // zero xx/yy (atomicAdd target)
  hipMemsetAsync(out + XY_ELEMS, 0, (size_t)2 * XSQ_ELEMS * sizeof(float),
                 stream);
  pass1<<<2048, 256, 0, stream>>>(x, y, xb, yb, out);
  pass2<<<256, 256, 0, stream>>>(xb, yb, ws2);
  pass3<<<1024, 256, 0, stream>>>(ws2, out);
}